// Round 1
// baseline (2070.841 us; speedup 1.0000x reference)
//
#include <hip/hip_runtime.h>
#include <float.h>
#include <math.h>

#define TT 6
#define NN 3200
#define EE 32000
#define BB 8
#define GF 128
#define TOKF 512
#define NHH 8

static __device__ __forceinline__ float leaky(float v){ return v > 0.f ? v : 0.2f*v; }

// ---------------- generic tiled f32 GEMM: C[M,N] = A[M,K]@W[K,N] + bias ----------------
__global__ __launch_bounds__(256) void gemm_tiled(
    const float* __restrict__ A, int lda,
    const float* __restrict__ W, int ldw,
    const float* __restrict__ bias,
    float* __restrict__ C, int ldc,
    int M, int N, int K, int do_relu)
{
  __shared__ float As[64][33];   // [row][k] padded
  __shared__ float Bs[32][64];   // [k][col]
  int tid = threadIdx.x;
  int tx = tid & 15, ty = tid >> 4;
  int m0 = blockIdx.y * 64, n0 = blockIdx.x * 64;
  float acc[4][4] = {};
  for (int k0 = 0; k0 < K; k0 += 32) {
    #pragma unroll
    for (int i = 0; i < 8; ++i) {
      int idx = tid + i * 256;
      int r = idx >> 5, kk = idx & 31;
      int m = m0 + r;
      As[r][kk] = (m < M) ? A[(size_t)m * lda + k0 + kk] : 0.f;
    }
    #pragma unroll
    for (int i = 0; i < 8; ++i) {
      int idx = tid + i * 256;
      int kk = idx >> 6, cc = idx & 63;
      int n = n0 + cc;
      Bs[kk][cc] = (n < N) ? W[(size_t)(k0 + kk) * ldw + n] : 0.f;
    }
    __syncthreads();
    #pragma unroll
    for (int kk = 0; kk < 32; ++kk) {
      float4 b4 = *(const float4*)&Bs[kk][tx * 4];
      float a0 = As[ty*4+0][kk];
      float a1 = As[ty*4+1][kk];
      float a2 = As[ty*4+2][kk];
      float a3 = As[ty*4+3][kk];
      acc[0][0] += a0*b4.x; acc[0][1] += a0*b4.y; acc[0][2] += a0*b4.z; acc[0][3] += a0*b4.w;
      acc[1][0] += a1*b4.x; acc[1][1] += a1*b4.y; acc[1][2] += a1*b4.z; acc[1][3] += a1*b4.w;
      acc[2][0] += a2*b4.x; acc[2][1] += a2*b4.y; acc[2][2] += a2*b4.z; acc[2][3] += a2*b4.w;
      acc[3][0] += a3*b4.x; acc[3][1] += a3*b4.y; acc[3][2] += a3*b4.z; acc[3][3] += a3*b4.w;
    }
    __syncthreads();
  }
  #pragma unroll
  for (int i = 0; i < 4; ++i) {
    int m = m0 + ty*4 + i;
    if (m >= M) continue;
    #pragma unroll
    for (int j = 0; j < 4; ++j) {
      int n = n0 + tx*4 + j;
      if (n >= N) continue;
      float v = acc[i][j] + bias[n];
      if (do_relu) v = fmaxf(v, 0.f);
      C[(size_t)m * ldc + n] = v;
    }
  }
}

// ---------------- CSR build ----------------
__global__ void k_hist(const int* __restrict__ edge_index, int* __restrict__ cnt)
{
  int gid = blockIdx.x * 256 + threadIdx.x;
  if (gid >= TT * EE) return;
  int t = gid / EE, e = gid - t * EE;
  int dst = edge_index[t * 2 * EE + EE + e];
  atomicAdd(&cnt[t * NN + dst], 1);
}

__global__ __launch_bounds__(256) void k_scan(const int* __restrict__ cnt, int* __restrict__ row)
{
  __shared__ int part[256];
  int t = blockIdx.x, tid = threadIdx.x;
  const int chunk = (NN + 255) / 256;   // 13
  int s0 = tid * chunk;
  int loc = 0;
  for (int i = 0; i < chunk; ++i) { int idx = s0 + i; if (idx < NN) loc += cnt[t*NN + idx]; }
  part[tid] = loc; __syncthreads();
  for (int off = 1; off < 256; off <<= 1) {
    int v = (tid >= off) ? part[tid - off] : 0;
    __syncthreads();
    part[tid] += v;
    __syncthreads();
  }
  int run = part[tid] - loc;   // exclusive prefix
  for (int i = 0; i < chunk; ++i) {
    int idx = s0 + i;
    if (idx < NN) { row[t*(NN+1) + idx] = run; run += cnt[t*NN + idx]; }
  }
  if (tid == 255) row[t*(NN+1) + NN] = part[255];
}

__global__ void k_scatter(const int* __restrict__ edge_index, const int* __restrict__ row,
                          int* __restrict__ cur, int* __restrict__ srcs,
                          int* __restrict__ dsts, int* __restrict__ eids)
{
  int gid = blockIdx.x * 256 + threadIdx.x;
  if (gid >= TT * EE) return;
  int t = gid / EE, e = gid - t * EE;
  int src = edge_index[t * 2 * EE + e];
  int dst = edge_index[t * 2 * EE + EE + e];
  int pos = row[t*(NN+1) + dst] + atomicAdd(&cur[t*NN + dst], 1);
  int s = t * EE + pos;
  srcs[s] = src; dsts[s] = dst; eids[s] = e;
}

__global__ void k_gstart(const int* __restrict__ batch, int* __restrict__ gs)
{
  int n = blockIdx.x * 256 + threadIdx.x;
  if (n >= NN) return;
  int bc = batch[n];
  if (n == 0) { for (int j = 0; j <= bc; ++j) gs[j] = 0; }
  else { int bp = batch[n-1]; for (int j = bp + 1; j <= bc; ++j) gs[j] = n; }
  if (n == NN - 1) { for (int j = bc + 1; j <= BB; ++j) gs[j] = NN; }
}

// ---------------- GAT edge logits (one wave per CSR slot) ----------------
__global__ __launch_bounds__(256) void k_edge_logits(
    const float* __restrict__ xlr, const int* __restrict__ srcs,
    const int* __restrict__ dsts, const int* __restrict__ eids,
    const float* __restrict__ ea, const float* __restrict__ we,
    const float* __restrict__ att, float* __restrict__ logits)
{
  int wave = threadIdx.x >> 6, lane = threadIdx.x & 63;
  int p = blockIdx.x * 4 + wave;
  int t = blockIdx.y;
  if (p >= EE) return;
  size_t s = (size_t)t * EE + p;
  int src = srcs[s], dst = dsts[s], eid = eids[s];
  float ea0 = ea[((size_t)t * EE + eid) * 2 + 0];
  float ea1 = ea[((size_t)t * EE + eid) * 2 + 1];
  const float* xs = xlr + ((size_t)t * NN + src) * 1024;         // xl[src]
  const float* xd = xlr + ((size_t)t * NN + dst) * 1024 + 512;   // xr[dst]
  float acc0 = 0.f, acc1 = 0.f, acc2 = 0.f, acc3 = 0.f;
  #pragma unroll
  for (int it = 0; it < 8; ++it) {
    int j = it * 64 + lane;          // j = h*128 + c
    float v = xs[j] + xd[j] + ea0 * we[j] + ea1 * we[512 + j];
    v = leaky(v);
    float contrib = v * att[j];
    if (it < 2) acc0 += contrib;
    else if (it < 4) acc1 += contrib;
    else if (it < 6) acc2 += contrib;
    else acc3 += contrib;
  }
  #pragma unroll
  for (int o = 32; o > 0; o >>= 1) {
    acc0 += __shfl_xor(acc0, o, 64);
    acc1 += __shfl_xor(acc1, o, 64);
    acc2 += __shfl_xor(acc2, o, 64);
    acc3 += __shfl_xor(acc3, o, 64);
  }
  if (lane < 4) {
    float v = (lane == 0) ? acc0 : (lane == 1) ? acc1 : (lane == 2) ? acc2 : acc3;
    logits[s * 4 + lane] = v;
  }
}

// ------------- GAT per-dst softmax + aggregate + head-mean + relu + residual + LN -------------
__global__ __launch_bounds__(128) void k_gat_aggregate(
    const float* __restrict__ xlr, const int* __restrict__ row,
    const int* __restrict__ srcs, const float* __restrict__ logits,
    float* __restrict__ alpha_g, const float* __restrict__ bias,
    const float* __restrict__ lng, const float* __restrict__ lnb,
    const float* __restrict__ h_in, float* __restrict__ h_out)
{
  __shared__ float mxs[4], ss[4];
  __shared__ float alphasm[1024];
  __shared__ float red[128];
  int t = blockIdx.y, n = blockIdx.x, c = threadIdx.x;
  int start = row[t*(NN+1) + n];
  int deg   = row[t*(NN+1) + n + 1] - start;
  size_t sbase = (size_t)t * EE + start;
  if (c < 4 && deg > 0) {
    float mx = -FLT_MAX;
    for (int p = 0; p < deg; ++p) mx = fmaxf(mx, logits[(sbase + p) * 4 + c]);
    float sum = 0.f;
    for (int p = 0; p < deg; ++p) sum += expf(logits[(sbase + p) * 4 + c] - mx);
    mxs[c] = mx; ss[c] = sum + 1e-16f;
  }
  __syncthreads();
  for (int idx = c; idx < deg * 4; idx += 128) {
    int p = idx >> 2, hh = idx & 3;
    float a = expf(logits[(sbase + p) * 4 + hh] - mxs[hh]) / ss[hh];
    if (idx < 1024) alphasm[idx] = a;
    else alpha_g[(sbase + p) * 4 + hh] = a;
  }
  __syncthreads();
  float acc = 0.f;
  for (int p = 0; p < deg; ++p) {
    int sp = srcs[sbase + p];
    const float* xb = xlr + ((size_t)t * NN + sp) * 1024;
    int ib = p * 4;
    float a0 = (ib + 0 < 1024) ? alphasm[ib + 0] : alpha_g[(sbase + p) * 4 + 0];
    float a1 = (ib + 1 < 1024) ? alphasm[ib + 1] : alpha_g[(sbase + p) * 4 + 1];
    float a2 = (ib + 2 < 1024) ? alphasm[ib + 2] : alpha_g[(sbase + p) * 4 + 2];
    float a3 = (ib + 3 < 1024) ? alphasm[ib + 3] : alpha_g[(sbase + p) * 4 + 3];
    acc += xb[c] * a0 + xb[128 + c] * a1 + xb[256 + c] * a2 + xb[384 + c] * a3;
  }
  float val = acc * 0.25f + bias[c];
  val = fmaxf(val, 0.f);
  float res = val + h_in[((size_t)t * NN + n) * 128 + c];
  red[c] = res; __syncthreads();
  for (int s2 = 64; s2 > 0; s2 >>= 1) { if (c < s2) red[c] += red[c + s2]; __syncthreads(); }
  float mu = red[0] * (1.f / 128.f); __syncthreads();
  float dv = res - mu;
  red[c] = dv * dv; __syncthreads();
  for (int s2 = 64; s2 > 0; s2 >>= 1) { if (c < s2) red[c] += red[c + s2]; __syncthreads(); }
  float rstd = rsqrtf(red[0] * (1.f / 128.f) + 1e-5f);
  h_out[((size_t)t * NN + n) * 128 + c] = dv * rstd * lng[c] + lnb[c];
}

// ---------------- graph pooling (mean + max) ----------------
__global__ __launch_bounds__(128) void k_pool(
    const float* __restrict__ h, const int* __restrict__ gs, float* __restrict__ pooled)
{
  int b = blockIdx.x, t = blockIdx.y, c = threadIdx.x;
  int s0 = gs[b], s1 = gs[b + 1];
  float sum = 0.f, mx = -FLT_MAX;
  for (int n = s0; n < s1; ++n) {
    float v = h[((size_t)t * NN + n) * 128 + c];
    sum += v; mx = fmaxf(mx, v);
  }
  float cntf = (float)(s1 - s0 > 0 ? s1 - s0 : 1);
  pooled[((size_t)t * BB + b) * 256 + c] = sum / cntf;
  pooled[((size_t)t * BB + b) * 256 + 128 + c] = mx;
}

// ---------------- transpose tokens[T,B,:] -> app[B,T,:] ----------------
__global__ void k_app(const float* __restrict__ tokens, float* __restrict__ happ)
{
  int gid = blockIdx.x * 256 + threadIdx.x;
  if (gid >= BB * TT * TOKF) return;
  int b = gid / (TT * TOKF);
  int r = gid - b * (TT * TOKF);
  int t = r / TOKF, j = r - t * TOKF;
  happ[gid] = tokens[((size_t)t * BB + b) * TOKF + j];
}

// ---------------- motion diff output ----------------
__global__ void k_mot(const float* __restrict__ tokens, float* __restrict__ out2)
{
  int gid = blockIdx.x * 256 + threadIdx.x;
  if (gid >= BB * (TT - 1) * 256) return;
  int b = gid / ((TT - 1) * 256);
  int r = gid - b * ((TT - 1) * 256);
  int ti = r / 256, cc = r - ti * 256;
  out2[gid] = tokens[((size_t)(ti + 1) * BB + b) * TOKF + cc]
            - tokens[((size_t)ti * BB + b) * TOKF + cc];
}

// ---------------- tiny MHA (B=8, T=6, NH=8, HD=64) ----------------
__global__ __launch_bounds__(64) void k_attn(const float* __restrict__ qkv, float* __restrict__ aout)
{
  __shared__ float qs[TT][64], ks[TT][64], vs[TT][64], sc[TT][TT];
  int h = blockIdx.x, b = blockIdx.y, d = threadIdx.x;
  for (int i = 0; i < TT; ++i) {
    size_t base = ((size_t)(b * TT + i)) * 1536 + h * 64 + d;
    qs[i][d] = qkv[base];
    ks[i][d] = qkv[base + 512];
    vs[i][d] = qkv[base + 1024];
  }
  __syncthreads();
  if (d < TT * TT) {
    int i = d / TT, j = d - i * TT;
    float s = 0.f;
    for (int k = 0; k < 64; ++k) s += qs[i][k] * ks[j][k];
    sc[i][j] = s * 0.125f;   // 1/sqrt(64)
  }
  __syncthreads();
  if (d < TT) {
    float mx = -FLT_MAX;
    for (int j = 0; j < TT; ++j) mx = fmaxf(mx, sc[d][j]);
    float sum = 0.f;
    for (int j = 0; j < TT; ++j) { float e = expf(sc[d][j] - mx); sc[d][j] = e; sum += e; }
    float inv = 1.f / sum;
    for (int j = 0; j < TT; ++j) sc[d][j] *= inv;
  }
  __syncthreads();
  for (int i = 0; i < TT; ++i) {
    float o = 0.f;
    for (int j = 0; j < TT; ++j) o += sc[i][j] * vs[j][d];
    aout[((size_t)(b * TT + i)) * 512 + h * 64 + d] = o;
  }
}

// ---------------- residual + LayerNorm (width 512) ----------------
__global__ __launch_bounds__(256) void k_res_ln(
    const float* __restrict__ a, const float* __restrict__ r,
    const float* __restrict__ g, const float* __restrict__ be,
    float* __restrict__ out)
{
  __shared__ float red[256];
  int rowi = blockIdx.x, tid = threadIdx.x;
  size_t base = (size_t)rowi * 512;
  float v0 = a[base + tid] + r[base + tid];
  float v1 = a[base + 256 + tid] + r[base + 256 + tid];
  red[tid] = v0 + v1; __syncthreads();
  for (int s2 = 128; s2 > 0; s2 >>= 1) { if (tid < s2) red[tid] += red[tid + s2]; __syncthreads(); }
  float mu = red[0] * (1.f / 512.f); __syncthreads();
  float d0 = v0 - mu, d1 = v1 - mu;
  red[tid] = d0 * d0 + d1 * d1; __syncthreads();
  for (int s2 = 128; s2 > 0; s2 >>= 1) { if (tid < s2) red[tid] += red[tid + s2]; __syncthreads(); }
  float rstd = rsqrtf(red[0] * (1.f / 512.f) + 1e-5f);
  out[base + tid]       = d0 * rstd * g[tid]       + be[tid];
  out[base + 256 + tid] = d1 * rstd * g[256 + tid] + be[256 + tid];
}

extern "C" void kernel_launch(void* const* d_in, const int* in_sizes, int n_in,
                              void* d_out, int out_size, void* d_ws, size_t ws_size,
                              hipStream_t stream)
{
  const float* x        = (const float*)d_in[0];
  const int*   eidx     = (const int*)  d_in[1];
  const float* eattr    = (const float*)d_in[2];
  const int*   batch    = (const int*)  d_in[3];
  const float* proj_w   = (const float*)d_in[4];
  const float* proj_b   = (const float*)d_in[5];
  const float* gat_wl   = (const float*)d_in[6];
  const float* gat_bl   = (const float*)d_in[7];
  const float* gat_wr   = (const float*)d_in[8];
  const float* gat_br   = (const float*)d_in[9];
  const float* gat_we   = (const float*)d_in[10];
  const float* gat_att  = (const float*)d_in[11];
  const float* gat_bias = (const float*)d_in[12];
  const float* ln_g     = (const float*)d_in[13];
  const float* ln_b     = (const float*)d_in[14];
  const float* n2t_w    = (const float*)d_in[15];
  const float* n2t_b    = (const float*)d_in[16];
  const float* tf_wqkv  = (const float*)d_in[17];
  const float* tf_bqkv  = (const float*)d_in[18];
  const float* tf_wo    = (const float*)d_in[19];
  const float* tf_bo    = (const float*)d_in[20];
  const float* tf_w1    = (const float*)d_in[21];
  const float* tf_b1    = (const float*)d_in[22];
  const float* tf_w2    = (const float*)d_in[23];
  const float* tf_b2    = (const float*)d_in[24];
  const float* tf_ln1g  = (const float*)d_in[25];
  const float* tf_ln1b  = (const float*)d_in[26];
  const float* tf_ln2g  = (const float*)d_in[27];
  const float* tf_ln2b  = (const float*)d_in[28];

  char* ws = (char*)d_ws;
  size_t off = 0;
  auto alloc = [&](size_t bytes) -> char* {
    char* p = ws + off;
    off += (bytes + 255) & ~(size_t)255;
    return p;
  };
  int*   cnt    = (int*)  alloc((size_t)TT * NN * 4);
  int*   row    = (int*)  alloc((size_t)TT * (NN + 1) * 4);
  int*   srcs   = (int*)  alloc((size_t)TT * EE * 4);
  int*   dsts   = (int*)  alloc((size_t)TT * EE * 4);
  int*   eids   = (int*)  alloc((size_t)TT * EE * 4);
  int*   gs     = (int*)  alloc((BB + 1) * 4);
  float* h0     = (float*)alloc((size_t)TT * NN * 128 * 4);
  float* h1     = (float*)alloc((size_t)TT * NN * 128 * 4);
  float* xlr    = (float*)alloc((size_t)TT * NN * 1024 * 4);
  float* logits = (float*)alloc((size_t)TT * EE * 4 * 4);
  float* alpha  = (float*)alloc((size_t)TT * EE * 4 * 4);
  float* pooled = (float*)alloc((size_t)TT * BB * 256 * 4);
  float* tokens = (float*)alloc((size_t)TT * BB * 512 * 4);
  float* happ   = (float*)alloc((size_t)BB * TT * 512 * 4);
  float* happ2  = (float*)alloc((size_t)BB * TT * 512 * 4);
  float* qkvb   = (float*)alloc((size_t)BB * TT * 1536 * 4);
  float* aoutb  = (float*)alloc((size_t)BB * TT * 512 * 4);
  float* aproj  = (float*)alloc((size_t)BB * TT * 512 * 4);
  float* ffb    = (float*)alloc((size_t)BB * TT * 2048 * 4);
  float* ff2o   = (float*)alloc((size_t)BB * TT * 512 * 4);
  if (off > ws_size) return;  // workspace too small -> fail loudly (d_out untouched)

  // ---- CSR build per timestep ----
  hipMemsetAsync(cnt, 0, (size_t)TT * NN * 4, stream);
  k_hist<<<(TT * EE + 255) / 256, 256, 0, stream>>>(eidx, cnt);
  k_scan<<<TT, 256, 0, stream>>>(cnt, row);
  hipMemsetAsync(cnt, 0, (size_t)TT * NN * 4, stream);
  k_scatter<<<(TT * EE + 255) / 256, 256, 0, stream>>>(eidx, row, cnt, srcs, dsts, eids);
  k_gstart<<<(NN + 255) / 256, 256, 0, stream>>>(batch, gs);

  // ---- input projection: h0 = x @ proj_w + proj_b ----
  gemm_tiled<<<dim3(2, (TT * NN) / 64), 256, 0, stream>>>(
      x, 128, proj_w, 128, proj_b, h0, 128, TT * NN, 128, 128, 0);

  // ---- GAT layers ----
  float* hcur = h0; float* hnext = h1;
  for (int l = 0; l < 3; ++l) {
    const float* wl  = gat_wl  + (size_t)l * 128 * 512;
    const float* wr  = gat_wr  + (size_t)l * 128 * 512;
    const float* bl  = gat_bl  + (size_t)l * 512;
    const float* br  = gat_br  + (size_t)l * 512;
    const float* we  = gat_we  + (size_t)l * 2 * 512;
    const float* att = gat_att + (size_t)l * 512;
    gemm_tiled<<<dim3(8, 300), 256, 0, stream>>>(hcur, 128, wl, 512, bl, xlr,       1024, TT * NN, 512, 128, 0);
    gemm_tiled<<<dim3(8, 300), 256, 0, stream>>>(hcur, 128, wr, 512, br, xlr + 512, 1024, TT * NN, 512, 128, 0);
    k_edge_logits<<<dim3(EE / 4, TT), 256, 0, stream>>>(xlr, srcs, dsts, eids, eattr, we, att, logits);
    k_gat_aggregate<<<dim3(NN, TT), 128, 0, stream>>>(xlr, row, srcs, logits, alpha,
        gat_bias + l * 128, ln_g + l * 128, ln_b + l * 128, hcur, hnext);
    float* tmp = hcur; hcur = hnext; hnext = tmp;
  }

  // ---- pooling + token projection + motion diff ----
  k_pool<<<dim3(BB, TT), 128, 0, stream>>>(hcur, gs, pooled);
  gemm_tiled<<<dim3(8, 1), 256, 0, stream>>>(pooled, 256, n2t_w, 512, n2t_b, tokens, 512, TT * BB, 512, 256, 0);
  k_app<<<(BB * TT * TOKF + 255) / 256, 256, 0, stream>>>(tokens, happ);
  k_mot<<<(BB * (TT - 1) * 256 + 255) / 256, 256, 0, stream>>>(tokens, (float*)d_out + BB * TT * TOKF);

  // ---- transformer encoder (2 layers, post-norm) ----
  float* hx = happ;
  for (int l = 0; l < 2; ++l) {
    gemm_tiled<<<dim3(24, 1), 256, 0, stream>>>(hx, 512, tf_wqkv + (size_t)l * 512 * 1536, 1536,
        tf_bqkv + l * 1536, qkvb, 1536, BB * TT, 1536, 512, 0);
    k_attn<<<dim3(NHH, BB), 64, 0, stream>>>(qkvb, aoutb);
    gemm_tiled<<<dim3(8, 1), 256, 0, stream>>>(aoutb, 512, tf_wo + (size_t)l * 512 * 512, 512,
        tf_bo + l * 512, aproj, 512, BB * TT, 512, 512, 0);
    k_res_ln<<<BB * TT, 256, 0, stream>>>(aproj, hx, tf_ln1g + l * 512, tf_ln1b + l * 512, happ2);
    gemm_tiled<<<dim3(32, 1), 256, 0, stream>>>(happ2, 512, tf_w1 + (size_t)l * 512 * 2048, 2048,
        tf_b1 + l * 2048, ffb, 2048, BB * TT, 2048, 512, 1);
    gemm_tiled<<<dim3(8, 1), 256, 0, stream>>>(ffb, 2048, tf_w2 + (size_t)l * 2048 * 512, 512,
        tf_b2 + l * 512, ff2o, 512, BB * TT, 512, 2048, 0);
    float* dst = (l == 1) ? (float*)d_out : happ;
    k_res_ln<<<BB * TT, 256, 0, stream>>>(ff2o, happ2, tf_ln2g + l * 512, tf_ln2b + l * 512, dst);
    hx = happ;
  }
}

// Round 2
// 873.816 us; speedup vs baseline: 2.3699x; 2.3699x over previous
//
#include <hip/hip_runtime.h>
#include <float.h>
#include <math.h>

#define TT 6
#define NN 3200
#define EE 32000
#define BB 8
#define GF 128
#define TOKF 512
#define NHH 8

static __device__ __forceinline__ float leaky(float v){ return v > 0.f ? v : 0.2f*v; }

// ---------------- tiled f32 GEMM (M%64==0, N%64==0, K%32==0): C = A@W + bias ----------------
template<int SITE>
__global__ __launch_bounds__(256) void gemm_tiled(
    const float* __restrict__ A, int lda,
    const float* __restrict__ W, int ldw,
    const float* __restrict__ bias,
    float* __restrict__ C, int ldc,
    int M, int N, int K)
{
  __shared__ float As[64][36];   // [row][k], stride 36 (16B-aligned, 2-way max conflict)
  __shared__ float Bs[32][64];   // [k][col]
  int tid = threadIdx.x;
  int tx = tid & 15, ty = tid >> 4;
  int m0 = blockIdx.y * 64, n0 = blockIdx.x * 64;
  float acc[4][4] = {};
  for (int k0 = 0; k0 < K; k0 += 32) {
    #pragma unroll
    for (int i = 0; i < 2; ++i) {
      int q = tid + i * 256;
      int r = q >> 3, k = (q & 7) * 4;
      *(float4*)&As[r][k] = *(const float4*)&A[(size_t)(m0 + r) * lda + k0 + k];
    }
    #pragma unroll
    for (int i = 0; i < 2; ++i) {
      int q = tid + i * 256;
      int kk = q >> 4, c = (q & 15) * 4;
      *(float4*)&Bs[kk][c] = *(const float4*)&W[(size_t)(k0 + kk) * ldw + n0 + c];
    }
    __syncthreads();
    #pragma unroll
    for (int kk = 0; kk < 32; ++kk) {
      float4 b4 = *(const float4*)&Bs[kk][tx * 4];
      float a0 = As[ty*4+0][kk];
      float a1 = As[ty*4+1][kk];
      float a2 = As[ty*4+2][kk];
      float a3 = As[ty*4+3][kk];
      acc[0][0] += a0*b4.x; acc[0][1] += a0*b4.y; acc[0][2] += a0*b4.z; acc[0][3] += a0*b4.w;
      acc[1][0] += a1*b4.x; acc[1][1] += a1*b4.y; acc[1][2] += a1*b4.z; acc[1][3] += a1*b4.w;
      acc[2][0] += a2*b4.x; acc[2][1] += a2*b4.y; acc[2][2] += a2*b4.z; acc[2][3] += a2*b4.w;
      acc[3][0] += a3*b4.x; acc[3][1] += a3*b4.y; acc[3][2] += a3*b4.z; acc[3][3] += a3*b4.w;
    }
    __syncthreads();
  }
  float4 bia = *(const float4*)&bias[n0 + tx * 4];
  #pragma unroll
  for (int i = 0; i < 4; ++i) {
    float4 v = { acc[i][0] + bia.x, acc[i][1] + bia.y, acc[i][2] + bia.z, acc[i][3] + bia.w };
    *(float4*)&C[(size_t)(m0 + ty*4 + i) * ldc + n0 + tx * 4] = v;
  }
}

// ---------------- fused GAT xl/xr GEMM: writes xlr[m][0:512]=A@wl+bl, [512:1024]=A@wr+br ----
__global__ __launch_bounds__(256) void gat_lr_gemm(
    const float* __restrict__ A,            // [M][128]
    const float* __restrict__ wl, const float* __restrict__ bl,
    const float* __restrict__ wr, const float* __restrict__ br,
    float* __restrict__ C)                  // [M][1024]
{
  __shared__ float As[64][36];
  __shared__ float Bs[32][64];
  int tid = threadIdx.x;
  int tx = tid & 15, ty = tid >> 4;
  int m0 = blockIdx.y * 64, n0 = blockIdx.x * 64;   // n0 in 0..1023
  const float* Wsel = (n0 < 512) ? wl : wr;
  const float* bsel = (n0 < 512) ? bl : br;
  int nb = (n0 < 512) ? n0 : n0 - 512;
  float acc[4][4] = {};
  for (int k0 = 0; k0 < 128; k0 += 32) {
    #pragma unroll
    for (int i = 0; i < 2; ++i) {
      int q = tid + i * 256;
      int r = q >> 3, k = (q & 7) * 4;
      *(float4*)&As[r][k] = *(const float4*)&A[(size_t)(m0 + r) * 128 + k0 + k];
    }
    #pragma unroll
    for (int i = 0; i < 2; ++i) {
      int q = tid + i * 256;
      int kk = q >> 4, c = (q & 15) * 4;
      *(float4*)&Bs[kk][c] = *(const float4*)&Wsel[(size_t)(k0 + kk) * 512 + nb + c];
    }
    __syncthreads();
    #pragma unroll
    for (int kk = 0; kk < 32; ++kk) {
      float4 b4 = *(const float4*)&Bs[kk][tx * 4];
      float a0 = As[ty*4+0][kk];
      float a1 = As[ty*4+1][kk];
      float a2 = As[ty*4+2][kk];
      float a3 = As[ty*4+3][kk];
      acc[0][0] += a0*b4.x; acc[0][1] += a0*b4.y; acc[0][2] += a0*b4.z; acc[0][3] += a0*b4.w;
      acc[1][0] += a1*b4.x; acc[1][1] += a1*b4.y; acc[1][2] += a1*b4.z; acc[1][3] += a1*b4.w;
      acc[2][0] += a2*b4.x; acc[2][1] += a2*b4.y; acc[2][2] += a2*b4.z; acc[2][3] += a2*b4.w;
      acc[3][0] += a3*b4.x; acc[3][1] += a3*b4.y; acc[3][2] += a3*b4.z; acc[3][3] += a3*b4.w;
    }
    __syncthreads();
  }
  float4 bia = *(const float4*)&bsel[nb + tx * 4];
  #pragma unroll
  for (int i = 0; i < 4; ++i) {
    float4 v = { acc[i][0] + bia.x, acc[i][1] + bia.y, acc[i][2] + bia.z, acc[i][3] + bia.w };
    *(float4*)&C[(size_t)(m0 + ty*4 + i) * 1024 + n0 + tx * 4] = v;
  }
}

// ---------------- split-K skinny GEMM (M=48): P[kc] = A[:, kc*128:+128] @ W-chunk ----------
__global__ __launch_bounds__(256) void gemm_part(
    const float* __restrict__ A, int lda,
    const float* __restrict__ W, int ldw,
    float* __restrict__ P, int N)
{
  __shared__ float As[48][132];
  __shared__ float Ws[128][32];
  int tid = threadIdx.x;
  int n0 = blockIdx.x * 32, k0 = blockIdx.y * 128;
  #pragma unroll
  for (int i = 0; i < 6; ++i) {
    int q = tid + i * 256;
    int m = q >> 5, k = (q & 31) * 4;
    *(float4*)&As[m][k] = *(const float4*)&A[(size_t)m * lda + k0 + k];
  }
  #pragma unroll
  for (int i = 0; i < 4; ++i) {
    int q = tid + i * 256;
    int k = q >> 3, c = (q & 7) * 4;
    *(float4*)&Ws[k][c] = *(const float4*)&W[(size_t)(k0 + k) * ldw + n0 + c];
  }
  __syncthreads();
  int tx = tid & 31, ty = tid >> 5;
  float acc[6] = {};
  #pragma unroll 4
  for (int k = 0; k < 128; ++k) {
    float w = Ws[k][tx];
    #pragma unroll
    for (int i = 0; i < 6; ++i) acc[i] += As[ty + 8*i][k] * w;
  }
  size_t base = (size_t)blockIdx.y * 48 * N;
  #pragma unroll
  for (int i = 0; i < 6; ++i)
    P[base + (size_t)(ty + 8*i) * N + n0 + tx] = acc[i];
}

__global__ void k_part_reduce(const float* __restrict__ P, const float* __restrict__ bias,
                              float* __restrict__ C, int MN, int N, int nparts, int relu)
{
  int i = blockIdx.x * 256 + threadIdx.x;
  if (i >= MN) return;
  float s = bias[i % N];
  for (int p = 0; p < nparts; ++p) s += P[(size_t)p * MN + i];
  C[i] = relu ? fmaxf(s, 0.f) : s;
}

// ---------------- CSR build ----------------
__global__ void k_hist(const int* __restrict__ edge_index, int* __restrict__ cnt)
{
  int gid = blockIdx.x * 256 + threadIdx.x;
  if (gid >= TT * EE) return;
  int t = gid / EE, e = gid - t * EE;
  int dst = edge_index[t * 2 * EE + EE + e];
  atomicAdd(&cnt[t * NN + dst], 1);
}

__global__ __launch_bounds__(256) void k_scan(const int* __restrict__ cnt, int* __restrict__ row)
{
  __shared__ int part[256];
  int t = blockIdx.x, tid = threadIdx.x;
  const int chunk = (NN + 255) / 256;   // 13
  int s0 = tid * chunk;
  int loc = 0;
  for (int i = 0; i < chunk; ++i) { int idx = s0 + i; if (idx < NN) loc += cnt[t*NN + idx]; }
  part[tid] = loc; __syncthreads();
  for (int off = 1; off < 256; off <<= 1) {
    int v = (tid >= off) ? part[tid - off] : 0;
    __syncthreads();
    part[tid] += v;
    __syncthreads();
  }
  int run = part[tid] - loc;   // exclusive prefix
  for (int i = 0; i < chunk; ++i) {
    int idx = s0 + i;
    if (idx < NN) { row[t*(NN+1) + idx] = run; run += cnt[t*NN + idx]; }
  }
  if (tid == 255) row[t*(NN+1) + NN] = part[255];
}

__global__ void k_scatter(const int* __restrict__ edge_index, const int* __restrict__ row,
                          int* __restrict__ cur, int* __restrict__ srcs,
                          int* __restrict__ dsts, int* __restrict__ eids)
{
  int gid = blockIdx.x * 256 + threadIdx.x;
  if (gid >= TT * EE) return;
  int t = gid / EE, e = gid - t * EE;
  int src = edge_index[t * 2 * EE + e];
  int dst = edge_index[t * 2 * EE + EE + e];
  int pos = row[t*(NN+1) + dst] + atomicAdd(&cur[t*NN + dst], 1);
  int s = t * EE + pos;
  srcs[s] = src; dsts[s] = dst; eids[s] = e;
}

__global__ void k_gstart(const int* __restrict__ batch, int* __restrict__ gs)
{
  int n = blockIdx.x * 256 + threadIdx.x;
  if (n >= NN) return;
  int bc = batch[n];
  if (n == 0) { for (int j = 0; j <= bc; ++j) gs[j] = 0; }
  else { int bp = batch[n-1]; for (int j = bp + 1; j <= bc; ++j) gs[j] = n; }
  if (n == NN - 1) { for (int j = bc + 1; j <= BB; ++j) gs[j] = NN; }
}

// ---------------- GAT edge logits (one wave per CSR slot) ----------------
__global__ __launch_bounds__(256) void k_edge_logits(
    const float* __restrict__ xlr, const int* __restrict__ srcs,
    const int* __restrict__ dsts, const int* __restrict__ eids,
    const float* __restrict__ ea, const float* __restrict__ we,
    const float* __restrict__ att, float* __restrict__ logits)
{
  int wave = threadIdx.x >> 6, lane = threadIdx.x & 63;
  int p = blockIdx.x * 4 + wave;
  int t = blockIdx.y;
  if (p >= EE) return;
  size_t s = (size_t)t * EE + p;
  int src = srcs[s], dst = dsts[s], eid = eids[s];
  float ea0 = ea[((size_t)t * EE + eid) * 2 + 0];
  float ea1 = ea[((size_t)t * EE + eid) * 2 + 1];
  const float* xs = xlr + ((size_t)t * NN + src) * 1024;         // xl[src]
  const float* xd = xlr + ((size_t)t * NN + dst) * 1024 + 512;   // xr[dst]
  float acc0 = 0.f, acc1 = 0.f, acc2 = 0.f, acc3 = 0.f;
  #pragma unroll
  for (int it = 0; it < 8; ++it) {
    int j = it * 64 + lane;          // j = h*128 + c
    float v = xs[j] + xd[j] + ea0 * we[j] + ea1 * we[512 + j];
    v = leaky(v);
    float contrib = v * att[j];
    if (it < 2) acc0 += contrib;
    else if (it < 4) acc1 += contrib;
    else if (it < 6) acc2 += contrib;
    else acc3 += contrib;
  }
  #pragma unroll
  for (int o = 32; o > 0; o >>= 1) {
    acc0 += __shfl_xor(acc0, o, 64);
    acc1 += __shfl_xor(acc1, o, 64);
    acc2 += __shfl_xor(acc2, o, 64);
    acc3 += __shfl_xor(acc3, o, 64);
  }
  if (lane < 4) {
    float v = (lane == 0) ? acc0 : (lane == 1) ? acc1 : (lane == 2) ? acc2 : acc3;
    logits[s * 4 + lane] = v;
  }
}

// ------------- GAT per-dst softmax + aggregate + head-mean + relu + residual + LN -------------
__global__ __launch_bounds__(128) void k_gat_aggregate(
    const float* __restrict__ xlr, const int* __restrict__ row,
    const int* __restrict__ srcs, const float* __restrict__ logits,
    float* __restrict__ alpha_g, const float* __restrict__ bias,
    const float* __restrict__ lng, const float* __restrict__ lnb,
    const float* __restrict__ h_in, float* __restrict__ h_out)
{
  __shared__ float mxs[4], ss[4];
  __shared__ float alphasm[1024];
  __shared__ float red[128];
  int t = blockIdx.y, n = blockIdx.x, c = threadIdx.x;
  int start = row[t*(NN+1) + n];
  int deg   = row[t*(NN+1) + n + 1] - start;
  size_t sbase = (size_t)t * EE + start;
  if (c < 4 && deg > 0) {
    float mx = -FLT_MAX;
    for (int p = 0; p < deg; ++p) mx = fmaxf(mx, logits[(sbase + p) * 4 + c]);
    float sum = 0.f;
    for (int p = 0; p < deg; ++p) sum += expf(logits[(sbase + p) * 4 + c] - mx);
    mxs[c] = mx; ss[c] = sum + 1e-16f;
  }
  __syncthreads();
  for (int idx = c; idx < deg * 4; idx += 128) {
    int p = idx >> 2, hh = idx & 3;
    float a = expf(logits[(sbase + p) * 4 + hh] - mxs[hh]) / ss[hh];
    if (idx < 1024) alphasm[idx] = a;
    else alpha_g[(sbase + p) * 4 + hh] = a;
  }
  __syncthreads();
  float acc = 0.f;
  for (int p = 0; p < deg; ++p) {
    int sp = srcs[sbase + p];
    const float* xb = xlr + ((size_t)t * NN + sp) * 1024;
    int ib = p * 4;
    float a0 = (ib + 0 < 1024) ? alphasm[ib + 0] : alpha_g[(sbase + p) * 4 + 0];
    float a1 = (ib + 1 < 1024) ? alphasm[ib + 1] : alpha_g[(sbase + p) * 4 + 1];
    float a2 = (ib + 2 < 1024) ? alphasm[ib + 2] : alpha_g[(sbase + p) * 4 + 2];
    float a3 = (ib + 3 < 1024) ? alphasm[ib + 3] : alpha_g[(sbase + p) * 4 + 3];
    acc += xb[c] * a0 + xb[128 + c] * a1 + xb[256 + c] * a2 + xb[384 + c] * a3;
  }
  float val = acc * 0.25f + bias[c];
  val = fmaxf(val, 0.f);
  float res = val + h_in[((size_t)t * NN + n) * 128 + c];
  red[c] = res; __syncthreads();
  for (int s2 = 64; s2 > 0; s2 >>= 1) { if (c < s2) red[c] += red[c + s2]; __syncthreads(); }
  float mu = red[0] * (1.f / 128.f); __syncthreads();
  float dv = res - mu;
  red[c] = dv * dv; __syncthreads();
  for (int s2 = 64; s2 > 0; s2 >>= 1) { if (c < s2) red[c] += red[c + s2]; __syncthreads(); }
  float rstd = rsqrtf(red[0] * (1.f / 128.f) + 1e-5f);
  h_out[((size_t)t * NN + n) * 128 + c] = dv * rstd * lng[c] + lnb[c];
}

// ---------------- graph pooling (mean + max) ----------------
__global__ __launch_bounds__(128) void k_pool(
    const float* __restrict__ h, const int* __restrict__ gs, float* __restrict__ pooled)
{
  int b = blockIdx.x, t = blockIdx.y, c = threadIdx.x;
  int s0 = gs[b], s1 = gs[b + 1];
  float sum = 0.f, mx = -FLT_MAX;
  for (int n = s0; n < s1; ++n) {
    float v = h[((size_t)t * NN + n) * 128 + c];
    sum += v; mx = fmaxf(mx, v);
  }
  float cntf = (float)(s1 - s0 > 0 ? s1 - s0 : 1);
  pooled[((size_t)t * BB + b) * 256 + c] = sum / cntf;
  pooled[((size_t)t * BB + b) * 256 + 128 + c] = mx;
}

// ---------------- transpose tokens[T,B,:] -> app[B,T,:] ----------------
__global__ void k_app(const float* __restrict__ tokens, float* __restrict__ happ)
{
  int gid = blockIdx.x * 256 + threadIdx.x;
  if (gid >= BB * TT * TOKF) return;
  int b = gid / (TT * TOKF);
  int r = gid - b * (TT * TOKF);
  int t = r / TOKF, j = r - t * TOKF;
  happ[gid] = tokens[((size_t)t * BB + b) * TOKF + j];
}

// ---------------- motion diff output ----------------
__global__ void k_mot(const float* __restrict__ tokens, float* __restrict__ out2)
{
  int gid = blockIdx.x * 256 + threadIdx.x;
  if (gid >= BB * (TT - 1) * 256) return;
  int b = gid / ((TT - 1) * 256);
  int r = gid - b * ((TT - 1) * 256);
  int ti = r / 256, cc = r - ti * 256;
  out2[gid] = tokens[((size_t)(ti + 1) * BB + b) * TOKF + cc]
            - tokens[((size_t)ti * BB + b) * TOKF + cc];
}

// ---------------- tiny MHA (B=8, T=6, NH=8, HD=64) ----------------
__global__ __launch_bounds__(64) void k_attn(const float* __restrict__ qkv, float* __restrict__ aout)
{
  __shared__ float qs[TT][64], ks[TT][64], vs[TT][64], sc[TT][TT];
  int h = blockIdx.x, b = blockIdx.y, d = threadIdx.x;
  for (int i = 0; i < TT; ++i) {
    size_t base = ((size_t)(b * TT + i)) * 1536 + h * 64 + d;
    qs[i][d] = qkv[base];
    ks[i][d] = qkv[base + 512];
    vs[i][d] = qkv[base + 1024];
  }
  __syncthreads();
  if (d < TT * TT) {
    int i = d / TT, j = d - i * TT;
    float s = 0.f;
    for (int k = 0; k < 64; ++k) s += qs[i][k] * ks[j][k];
    sc[i][j] = s * 0.125f;   // 1/sqrt(64)
  }
  __syncthreads();
  if (d < TT) {
    float mx = -FLT_MAX;
    for (int j = 0; j < TT; ++j) mx = fmaxf(mx, sc[d][j]);
    float sum = 0.f;
    for (int j = 0; j < TT; ++j) { float e = expf(sc[d][j] - mx); sc[d][j] = e; sum += e; }
    float inv = 1.f / sum;
    for (int j = 0; j < TT; ++j) sc[d][j] *= inv;
  }
  __syncthreads();
  for (int i = 0; i < TT; ++i) {
    float o = 0.f;
    for (int j = 0; j < TT; ++j) o += sc[i][j] * vs[j][d];
    aout[((size_t)(b * TT + i)) * 512 + h * 64 + d] = o;
  }
}

// ---------------- residual + LayerNorm (width 512) ----------------
__global__ __launch_bounds__(256) void k_res_ln(
    const float* __restrict__ a, const float* __restrict__ r,
    const float* __restrict__ g, const float* __restrict__ be,
    float* __restrict__ out)
{
  __shared__ float red[256];
  int rowi = blockIdx.x, tid = threadIdx.x;
  size_t base = (size_t)rowi * 512;
  float v0 = a[base + tid] + r[base + tid];
  float v1 = a[base + 256 + tid] + r[base + 256 + tid];
  red[tid] = v0 + v1; __syncthreads();
  for (int s2 = 128; s2 > 0; s2 >>= 1) { if (tid < s2) red[tid] += red[tid + s2]; __syncthreads(); }
  float mu = red[0] * (1.f / 512.f); __syncthreads();
  float d0 = v0 - mu, d1 = v1 - mu;
  red[tid] = d0 * d0 + d1 * d1; __syncthreads();
  for (int s2 = 128; s2 > 0; s2 >>= 1) { if (tid < s2) red[tid] += red[tid + s2]; __syncthreads(); }
  float rstd = rsqrtf(red[0] * (1.f / 512.f) + 1e-5f);
  out[base + tid]       = d0 * rstd * g[tid]       + be[tid];
  out[base + 256 + tid] = d1 * rstd * g[256 + tid] + be[256 + tid];
}

extern "C" void kernel_launch(void* const* d_in, const int* in_sizes, int n_in,
                              void* d_out, int out_size, void* d_ws, size_t ws_size,
                              hipStream_t stream)
{
  const float* x        = (const float*)d_in[0];
  const int*   eidx     = (const int*)  d_in[1];
  const float* eattr    = (const float*)d_in[2];
  const int*   batch    = (const int*)  d_in[3];
  const float* proj_w   = (const float*)d_in[4];
  const float* proj_b   = (const float*)d_in[5];
  const float* gat_wl   = (const float*)d_in[6];
  const float* gat_bl   = (const float*)d_in[7];
  const float* gat_wr   = (const float*)d_in[8];
  const float* gat_br   = (const float*)d_in[9];
  const float* gat_we   = (const float*)d_in[10];
  const float* gat_att  = (const float*)d_in[11];
  const float* gat_bias = (const float*)d_in[12];
  const float* ln_g     = (const float*)d_in[13];
  const float* ln_b     = (const float*)d_in[14];
  const float* n2t_w    = (const float*)d_in[15];
  const float* n2t_b    = (const float*)d_in[16];
  const float* tf_wqkv  = (const float*)d_in[17];
  const float* tf_bqkv  = (const float*)d_in[18];
  const float* tf_wo    = (const float*)d_in[19];
  const float* tf_bo    = (const float*)d_in[20];
  const float* tf_w1    = (const float*)d_in[21];
  const float* tf_b1    = (const float*)d_in[22];
  const float* tf_w2    = (const float*)d_in[23];
  const float* tf_b2    = (const float*)d_in[24];
  const float* tf_ln1g  = (const float*)d_in[25];
  const float* tf_ln1b  = (const float*)d_in[26];
  const float* tf_ln2g  = (const float*)d_in[27];
  const float* tf_ln2b  = (const float*)d_in[28];

  char* ws = (char*)d_ws;
  size_t off = 0;
  auto alloc = [&](size_t bytes) -> char* {
    char* p = ws + off;
    off += (bytes + 255) & ~(size_t)255;
    return p;
  };
  int*   cnt    = (int*)  alloc((size_t)TT * NN * 4);
  int*   row    = (int*)  alloc((size_t)TT * (NN + 1) * 4);
  int*   srcs   = (int*)  alloc((size_t)TT * EE * 4);
  int*   dsts   = (int*)  alloc((size_t)TT * EE * 4);
  int*   eids   = (int*)  alloc((size_t)TT * EE * 4);
  int*   gs     = (int*)  alloc((BB + 1) * 4);
  float* h0     = (float*)alloc((size_t)TT * NN * 128 * 4);
  float* h1     = (float*)alloc((size_t)TT * NN * 128 * 4);
  float* xlr    = (float*)alloc((size_t)TT * NN * 1024 * 4);
  float* logits = (float*)alloc((size_t)TT * EE * 4 * 4);
  float* alpha  = (float*)alloc((size_t)TT * EE * 4 * 4);
  float* pooled = (float*)alloc((size_t)TT * BB * 256 * 4);
  float* tokens = (float*)alloc((size_t)TT * BB * 512 * 4);
  float* happ   = (float*)alloc((size_t)BB * TT * 512 * 4);
  float* happ2  = (float*)alloc((size_t)BB * TT * 512 * 4);
  float* qkvb   = (float*)alloc((size_t)BB * TT * 1536 * 4);
  float* aoutb  = (float*)alloc((size_t)BB * TT * 512 * 4);
  float* aproj  = (float*)alloc((size_t)BB * TT * 512 * 4);
  float* ffb    = (float*)alloc((size_t)BB * TT * 2048 * 4);
  float* ff2o   = (float*)alloc((size_t)BB * TT * 512 * 4);
  if (off > ws_size) return;  // workspace too small -> fail loudly (d_out untouched)

  // split-K partial buffer aliases xlr (dead once the GAT phase is finished;
  // first gemm_part runs after last k_gat_aggregate)
  float* P = xlr;

  // ---- CSR build per timestep ----
  hipMemsetAsync(cnt, 0, (size_t)TT * NN * 4, stream);
  k_hist<<<(TT * EE + 255) / 256, 256, 0, stream>>>(eidx, cnt);
  k_scan<<<TT, 256, 0, stream>>>(cnt, row);
  hipMemsetAsync(cnt, 0, (size_t)TT * NN * 4, stream);
  k_scatter<<<(TT * EE + 255) / 256, 256, 0, stream>>>(eidx, row, cnt, srcs, dsts, eids);
  k_gstart<<<(NN + 255) / 256, 256, 0, stream>>>(batch, gs);

  // ---- input projection: h0 = x @ proj_w + proj_b ----
  gemm_tiled<0><<<dim3(2, (TT * NN) / 64), 256, 0, stream>>>(
      x, 128, proj_w, 128, proj_b, h0, 128, TT * NN, 128, 128);

  // ---- GAT layers ----
  float* hcur = h0; float* hnext = h1;
  for (int l = 0; l < 3; ++l) {
    const float* wl  = gat_wl  + (size_t)l * 128 * 512;
    const float* wr  = gat_wr  + (size_t)l * 128 * 512;
    const float* bl  = gat_bl  + (size_t)l * 512;
    const float* br  = gat_br  + (size_t)l * 512;
    const float* we  = gat_we  + (size_t)l * 2 * 512;
    const float* att = gat_att + (size_t)l * 512;
    gat_lr_gemm<<<dim3(16, 300), 256, 0, stream>>>(hcur, wl, bl, wr, br, xlr);
    k_edge_logits<<<dim3(EE / 4, TT), 256, 0, stream>>>(xlr, srcs, dsts, eids, eattr, we, att, logits);
    k_gat_aggregate<<<dim3(NN, TT), 128, 0, stream>>>(xlr, row, srcs, logits, alpha,
        gat_bias + l * 128, ln_g + l * 128, ln_b + l * 128, hcur, hnext);
    float* tmp = hcur; hcur = hnext; hnext = tmp;
  }

  // ---- pooling + token projection + motion diff ----
  k_pool<<<dim3(BB, TT), 128, 0, stream>>>(hcur, gs, pooled);
  gemm_part<<<dim3(512 / 32, 2), 256, 0, stream>>>(pooled, 256, n2t_w, 512, P, 512);
  k_part_reduce<<<(48 * 512 + 255) / 256, 256, 0, stream>>>(P, n2t_b, tokens, 48 * 512, 512, 2, 0);
  k_app<<<(BB * TT * TOKF + 255) / 256, 256, 0, stream>>>(tokens, happ);
  k_mot<<<(BB * (TT - 1) * 256 + 255) / 256, 256, 0, stream>>>(tokens, (float*)d_out + BB * TT * TOKF);

  // ---- transformer encoder (2 layers, post-norm) ----
  float* hx = happ;
  for (int l = 0; l < 2; ++l) {
    gemm_part<<<dim3(1536 / 32, 4), 256, 0, stream>>>(hx, 512,
        tf_wqkv + (size_t)l * 512 * 1536, 1536, P, 1536);
    k_part_reduce<<<(48 * 1536 + 255) / 256, 256, 0, stream>>>(P, tf_bqkv + l * 1536, qkvb, 48 * 1536, 1536, 4, 0);
    k_attn<<<dim3(NHH, BB), 64, 0, stream>>>(qkvb, aoutb);
    gemm_part<<<dim3(512 / 32, 4), 256, 0, stream>>>(aoutb, 512,
        tf_wo + (size_t)l * 512 * 512, 512, P, 512);
    k_part_reduce<<<(48 * 512 + 255) / 256, 256, 0, stream>>>(P, tf_bo + l * 512, aproj, 48 * 512, 512, 4, 0);
    k_res_ln<<<BB * TT, 256, 0, stream>>>(aproj, hx, tf_ln1g + l * 512, tf_ln1b + l * 512, happ2);
    gemm_part<<<dim3(2048 / 32, 4), 256, 0, stream>>>(happ2, 512,
        tf_w1 + (size_t)l * 512 * 2048, 2048, P, 2048);
    k_part_reduce<<<(48 * 2048 + 255) / 256, 256, 0, stream>>>(P, tf_b1 + l * 2048, ffb, 48 * 2048, 2048, 4, 1);
    gemm_part<<<dim3(512 / 32, 16), 256, 0, stream>>>(ffb, 2048,
        tf_w2 + (size_t)l * 2048 * 512, 512, P, 512);
    k_part_reduce<<<(48 * 512 + 255) / 256, 256, 0, stream>>>(P, tf_b2 + l * 512, ff2o, 48 * 512, 512, 16, 0);
    float* dst = (l == 1) ? (float*)d_out : happ;
    k_res_ln<<<BB * TT, 256, 0, stream>>>(ff2o, happ2, tf_ln2g + l * 512, tf_ln2b + l * 512, dst);
    hx = happ;
  }
}

// Round 3
// 677.871 us; speedup vs baseline: 3.0549x; 1.2891x over previous
//
#include <hip/hip_runtime.h>
#include <float.h>
#include <math.h>

#define TT 6
#define NN 3200
#define EE 32000
#define BB 8
#define GF 128
#define TOKF 512
#define NHH 8
#define PCH 16   // pooling chunks per graph

typedef __attribute__((ext_vector_type(4))) float f32x4;
typedef __attribute__((ext_vector_type(8))) short short8;

static __device__ __forceinline__ float leaky(float v){ return v > 0.f ? v : 0.2f*v; }
static __device__ __forceinline__ ushort f2bf(float f) {
  uint u = __float_as_uint(f);
  uint r = (u + 0x7fffu + ((u >> 16) & 1u)) >> 16;
  return (ushort)r;
}
static __device__ __forceinline__ float bf2f(uint bits) {
  return __uint_as_float(bits << 16);
}

// ---------------- tiled f32 GEMM (proj only): C = A@W + bias ----------------
__global__ __launch_bounds__(256) void gemm_tiled(
    const float* __restrict__ A, int lda,
    const float* __restrict__ W, int ldw,
    const float* __restrict__ bias,
    float* __restrict__ C, int ldc,
    int M, int N, int K)
{
  __shared__ float As[64][36];
  __shared__ float Bs[32][64];
  int tid = threadIdx.x;
  int tx = tid & 15, ty = tid >> 4;
  int m0 = blockIdx.y * 64, n0 = blockIdx.x * 64;
  float acc[4][4] = {};
  for (int k0 = 0; k0 < K; k0 += 32) {
    #pragma unroll
    for (int i = 0; i < 2; ++i) {
      int q = tid + i * 256;
      int r = q >> 3, k = (q & 7) * 4;
      *(float4*)&As[r][k] = *(const float4*)&A[(size_t)(m0 + r) * lda + k0 + k];
    }
    #pragma unroll
    for (int i = 0; i < 2; ++i) {
      int q = tid + i * 256;
      int kk = q >> 4, c = (q & 15) * 4;
      *(float4*)&Bs[kk][c] = *(const float4*)&W[(size_t)(k0 + kk) * ldw + n0 + c];
    }
    __syncthreads();
    #pragma unroll
    for (int kk = 0; kk < 32; ++kk) {
      float4 b4 = *(const float4*)&Bs[kk][tx * 4];
      float a0 = As[ty*4+0][kk];
      float a1 = As[ty*4+1][kk];
      float a2 = As[ty*4+2][kk];
      float a3 = As[ty*4+3][kk];
      acc[0][0] += a0*b4.x; acc[0][1] += a0*b4.y; acc[0][2] += a0*b4.z; acc[0][3] += a0*b4.w;
      acc[1][0] += a1*b4.x; acc[1][1] += a1*b4.y; acc[1][2] += a1*b4.z; acc[1][3] += a1*b4.w;
      acc[2][0] += a2*b4.x; acc[2][1] += a2*b4.y; acc[2][2] += a2*b4.z; acc[2][3] += a2*b4.w;
      acc[3][0] += a3*b4.x; acc[3][1] += a3*b4.y; acc[3][2] += a3*b4.z; acc[3][3] += a3*b4.w;
    }
    __syncthreads();
  }
  float4 bia = *(const float4*)&bias[n0 + tx * 4];
  #pragma unroll
  for (int i = 0; i < 4; ++i) {
    float4 v = { acc[i][0] + bia.x, acc[i][1] + bia.y, acc[i][2] + bia.z, acc[i][3] + bia.w };
    *(float4*)&C[(size_t)(m0 + ty*4 + i) * ldc + n0 + tx * 4] = v;
  }
}

// ---------------- weight prep: Wt[n][k] bf16, n<512 from wl, else wr ----------------
__global__ void k_wprep(const float* __restrict__ wl, const float* __restrict__ wr,
                        ushort* __restrict__ Wt)
{
  int gid = blockIdx.x * 256 + threadIdx.x;
  if (gid >= 1024 * 128) return;
  int n = gid >> 7, k = gid & 127;
  float v = (n < 512) ? wl[(size_t)k * 512 + n] : wr[(size_t)k * 512 + (n - 512)];
  Wt[gid] = f2bf(v);
}

// ---------------- MFMA GAT xl/xr GEMM: xlr[m][0:512]=h@wl+bl, [512:1024]=h@wr+br (bf16 out) ----
__global__ __launch_bounds__(256) void gat_lr_gemm_mfma(
    const float* __restrict__ A,      // [M][128] f32
    const ushort* __restrict__ Wt,    // [1024][128] bf16 (transposed weights)
    const float* __restrict__ bl, const float* __restrict__ br,
    ushort* __restrict__ C)           // [M][1024] bf16
{
  __shared__ ushort Asm[64 * 128];
  __shared__ ushort Wsm[64 * 128];
  int tid = threadIdx.x;
  int m0 = blockIdx.y * 64, n0 = blockIdx.x * 64;

  // stage A (f32 -> bf16), XOR-swizzled granules (granule = 8 bf16 = 16B)
  #pragma unroll
  for (int i = 0; i < 4; ++i) {
    int g = tid + i * 256;            // 0..1023
    int row = g >> 4, gk = g & 15;
    const float* src = A + (size_t)(m0 + row) * 128 + gk * 8;
    float4 f0 = *(const float4*)src;
    float4 f1 = *(const float4*)(src + 4);
    short8 hv;
    hv[0] = (short)f2bf(f0.x); hv[1] = (short)f2bf(f0.y);
    hv[2] = (short)f2bf(f0.z); hv[3] = (short)f2bf(f0.w);
    hv[4] = (short)f2bf(f1.x); hv[5] = (short)f2bf(f1.y);
    hv[6] = (short)f2bf(f1.z); hv[7] = (short)f2bf(f1.w);
    *(short8*)&Asm[row * 128 + (gk ^ (row & 7)) * 8] = hv;
  }
  // stage Wt rows n0..n0+63 (already bf16), same swizzle
  #pragma unroll
  for (int i = 0; i < 4; ++i) {
    int g = tid + i * 256;
    int col = g >> 4, gk = g & 15;
    short8 raw = *(const short8*)&Wt[(size_t)(n0 + col) * 128 + gk * 8];
    *(short8*)&Wsm[col * 128 + (gk ^ (col & 7)) * 8] = raw;
  }
  __syncthreads();

  int l = tid & 63, wv = tid >> 6;
  int wr_ = wv >> 1, wc_ = wv & 1;      // 2x2 wave grid, wave tile 32x32
  int lr = l & 15, lk = l >> 4;         // lk in 0..3
  f32x4 acc[2][2] = {};
  #pragma unroll
  for (int ks = 0; ks < 4; ++ks) {      // K = 4 x 32
    int g = ks * 4 + lk;
    int ra0 = wr_ * 32 + lr,      ra1 = wr_ * 32 + 16 + lr;
    int rb0 = wc_ * 32 + lr,      rb1 = wc_ * 32 + 16 + lr;
    short8 a0 = *(short8*)&Asm[ra0 * 128 + (g ^ (ra0 & 7)) * 8];
    short8 a1 = *(short8*)&Asm[ra1 * 128 + (g ^ (ra1 & 7)) * 8];
    short8 b0 = *(short8*)&Wsm[rb0 * 128 + (g ^ (rb0 & 7)) * 8];
    short8 b1 = *(short8*)&Wsm[rb1 * 128 + (g ^ (rb1 & 7)) * 8];
    acc[0][0] = __builtin_amdgcn_mfma_f32_16x16x32_bf16(a0, b0, acc[0][0], 0, 0, 0);
    acc[0][1] = __builtin_amdgcn_mfma_f32_16x16x32_bf16(a0, b1, acc[0][1], 0, 0, 0);
    acc[1][0] = __builtin_amdgcn_mfma_f32_16x16x32_bf16(a1, b0, acc[1][0], 0, 0, 0);
    acc[1][1] = __builtin_amdgcn_mfma_f32_16x16x32_bf16(a1, b1, acc[1][1], 0, 0, 0);
  }

  int col_l = l & 15, row_l = (l >> 4) * 4;
  #pragma unroll
  for (int fn = 0; fn < 2; ++fn) {
    int n_g = n0 + wc_ * 32 + fn * 16 + col_l;
    float bia = (n_g < 512) ? bl[n_g] : br[n_g - 512];
    #pragma unroll
    for (int fm = 0; fm < 2; ++fm) {
      #pragma unroll
      for (int r = 0; r < 4; ++r) {
        int m = m0 + wr_ * 32 + fm * 16 + row_l + r;
        C[(size_t)m * 1024 + n_g] = f2bf(acc[fm][fn][r] + bia);
      }
    }
  }
}

// ---------------- split-K skinny GEMM (M=48) ----------------
__global__ __launch_bounds__(256) void gemm_part(
    const float* __restrict__ A, int lda,
    const float* __restrict__ W, int ldw,
    float* __restrict__ P, int N)
{
  __shared__ float As[48][132];
  __shared__ float Ws[128][32];
  int tid = threadIdx.x;
  int n0 = blockIdx.x * 32, k0 = blockIdx.y * 128;
  #pragma unroll
  for (int i = 0; i < 6; ++i) {
    int q = tid + i * 256;
    int m = q >> 5, k = (q & 31) * 4;
    *(float4*)&As[m][k] = *(const float4*)&A[(size_t)m * lda + k0 + k];
  }
  #pragma unroll
  for (int i = 0; i < 4; ++i) {
    int q = tid + i * 256;
    int k = q >> 3, c = (q & 7) * 4;
    *(float4*)&Ws[k][c] = *(const float4*)&W[(size_t)(k0 + k) * ldw + n0 + c];
  }
  __syncthreads();
  int tx = tid & 31, ty = tid >> 5;
  float acc[6] = {};
  #pragma unroll 4
  for (int k = 0; k < 128; ++k) {
    float w = Ws[k][tx];
    #pragma unroll
    for (int i = 0; i < 6; ++i) acc[i] += As[ty + 8*i][k] * w;
  }
  size_t base = (size_t)blockIdx.y * 48 * N;
  #pragma unroll
  for (int i = 0; i < 6; ++i)
    P[base + (size_t)(ty + 8*i) * N + n0 + tx] = acc[i];
}

__global__ void k_part_reduce(const float* __restrict__ P, const float* __restrict__ bias,
                              float* __restrict__ C, int MN, int N, int nparts, int relu)
{
  int i = blockIdx.x * 256 + threadIdx.x;
  if (i >= MN) return;
  float s = bias[i % N];
  for (int p = 0; p < nparts; ++p) s += P[(size_t)p * MN + i];
  C[i] = relu ? fmaxf(s, 0.f) : s;
}

// ---------------- CSR build ----------------
__global__ void k_hist(const int* __restrict__ edge_index, int* __restrict__ cnt)
{
  int gid = blockIdx.x * 256 + threadIdx.x;
  if (gid >= TT * EE) return;
  int t = gid / EE, e = gid - t * EE;
  int dst = edge_index[t * 2 * EE + EE + e];
  atomicAdd(&cnt[t * NN + dst], 1);
}

__global__ __launch_bounds__(256) void k_scan(const int* __restrict__ cnt, int* __restrict__ row)
{
  __shared__ int part[256];
  int t = blockIdx.x, tid = threadIdx.x;
  const int chunk = (NN + 255) / 256;
  int s0 = tid * chunk;
  int loc = 0;
  for (int i = 0; i < chunk; ++i) { int idx = s0 + i; if (idx < NN) loc += cnt[t*NN + idx]; }
  part[tid] = loc; __syncthreads();
  for (int off = 1; off < 256; off <<= 1) {
    int v = (tid >= off) ? part[tid - off] : 0;
    __syncthreads();
    part[tid] += v;
    __syncthreads();
  }
  int run = part[tid] - loc;
  for (int i = 0; i < chunk; ++i) {
    int idx = s0 + i;
    if (idx < NN) { row[t*(NN+1) + idx] = run; run += cnt[t*NN + idx]; }
  }
  if (tid == 255) row[t*(NN+1) + NN] = part[255];
}

__global__ void k_scatter(const int* __restrict__ edge_index, const int* __restrict__ row,
                          int* __restrict__ cur, int* __restrict__ srcs,
                          int* __restrict__ dsts, int* __restrict__ eids)
{
  int gid = blockIdx.x * 256 + threadIdx.x;
  if (gid >= TT * EE) return;
  int t = gid / EE, e = gid - t * EE;
  int src = edge_index[t * 2 * EE + e];
  int dst = edge_index[t * 2 * EE + EE + e];
  int pos = row[t*(NN+1) + dst] + atomicAdd(&cur[t*NN + dst], 1);
  int s = t * EE + pos;
  srcs[s] = src; dsts[s] = dst; eids[s] = e;
}

__global__ void k_gstart(const int* __restrict__ batch, int* __restrict__ gs)
{
  int n = blockIdx.x * 256 + threadIdx.x;
  if (n >= NN) return;
  int bc = batch[n];
  if (n == 0) { for (int j = 0; j <= bc; ++j) gs[j] = 0; }
  else { int bp = batch[n-1]; for (int j = bp + 1; j <= bc; ++j) gs[j] = n; }
  if (n == NN - 1) { for (int j = bc + 1; j <= BB; ++j) gs[j] = NN; }
}

// ---------------- GAT edge logits (bf16 xlr, one wave per CSR slot) ----------------
__global__ __launch_bounds__(256) void k_edge_logits(
    const ushort* __restrict__ xlr, const int* __restrict__ srcs,
    const int* __restrict__ dsts, const int* __restrict__ eids,
    const float* __restrict__ ea, const float* __restrict__ we,
    const float* __restrict__ att, float* __restrict__ logits)
{
  int wave = threadIdx.x >> 6, lane = threadIdx.x & 63;
  int p = blockIdx.x * 4 + wave;
  int t = blockIdx.y;
  if (p >= EE) return;
  size_t s = (size_t)t * EE + p;
  int src = srcs[s], dst = dsts[s], eid = eids[s];
  float ea0 = ea[((size_t)t * EE + eid) * 2 + 0];
  float ea1 = ea[((size_t)t * EE + eid) * 2 + 1];
  const uint* xs = (const uint*)(xlr + ((size_t)t * NN + src) * 1024);        // xl[src]
  const uint* xd = (const uint*)(xlr + ((size_t)t * NN + dst) * 1024 + 512);  // xr[dst]
  float hacc[4];
  #pragma unroll
  for (int it = 0; it < 4; ++it) {        // it == head
    int idx = it * 64 + lane;             // uint index; j0 = 2*idx
    uint us = xs[idx], ud = xd[idx];
    int j0 = idx * 2;
    float v0 = bf2f(us & 0xffffu) + bf2f(ud & 0xffffu) + ea0 * we[j0]     + ea1 * we[512 + j0];
    float v1 = bf2f(us >> 16)     + bf2f(ud >> 16)     + ea0 * we[j0 + 1] + ea1 * we[512 + j0 + 1];
    hacc[it] = leaky(v0) * att[j0] + leaky(v1) * att[j0 + 1];
  }
  #pragma unroll
  for (int o = 32; o > 0; o >>= 1) {
    hacc[0] += __shfl_xor(hacc[0], o, 64);
    hacc[1] += __shfl_xor(hacc[1], o, 64);
    hacc[2] += __shfl_xor(hacc[2], o, 64);
    hacc[3] += __shfl_xor(hacc[3], o, 64);
  }
  if (lane < 4) {
    float v = (lane == 0) ? hacc[0] : (lane == 1) ? hacc[1] : (lane == 2) ? hacc[2] : hacc[3];
    logits[s * 4 + lane] = v;
  }
}

// ------------- GAT per-dst softmax + aggregate + head-mean + relu + residual + LN -------------
__global__ __launch_bounds__(128) void k_gat_aggregate(
    const ushort* __restrict__ xlr, const int* __restrict__ row,
    const int* __restrict__ srcs, const float* __restrict__ logits,
    float* __restrict__ alpha_g, const float* __restrict__ bias,
    const float* __restrict__ lng, const float* __restrict__ lnb,
    const float* __restrict__ h_in, float* __restrict__ h_out)
{
  __shared__ float mxs[4], ss[4];
  __shared__ float alphasm[1024];
  __shared__ float red[128];
  int t = blockIdx.y, n = blockIdx.x, c = threadIdx.x;
  int start = row[t*(NN+1) + n];
  int deg   = row[t*(NN+1) + n + 1] - start;
  size_t sbase = (size_t)t * EE + start;
  if (c < 4 && deg > 0) {
    float mx = -FLT_MAX;
    for (int p = 0; p < deg; ++p) mx = fmaxf(mx, logits[(sbase + p) * 4 + c]);
    float sum = 0.f;
    for (int p = 0; p < deg; ++p) sum += expf(logits[(sbase + p) * 4 + c] - mx);
    mxs[c] = mx; ss[c] = sum + 1e-16f;
  }
  __syncthreads();
  for (int idx = c; idx < deg * 4; idx += 128) {
    int p = idx >> 2, hh = idx & 3;
    float a = expf(logits[(sbase + p) * 4 + hh] - mxs[hh]) / ss[hh];
    if (idx < 1024) alphasm[idx] = a;
    else alpha_g[(sbase + p) * 4 + hh] = a;
  }
  __syncthreads();
  float acc = 0.f;
  for (int p = 0; p < deg; ++p) {
    int sp = srcs[sbase + p];
    const ushort* xb = xlr + ((size_t)t * NN + sp) * 1024;
    int ib = p * 4;
    float a0 = (ib + 0 < 1024) ? alphasm[ib + 0] : alpha_g[(sbase + p) * 4 + 0];
    float a1 = (ib + 1 < 1024) ? alphasm[ib + 1] : alpha_g[(sbase + p) * 4 + 1];
    float a2 = (ib + 2 < 1024) ? alphasm[ib + 2] : alpha_g[(sbase + p) * 4 + 2];
    float a3 = (ib + 3 < 1024) ? alphasm[ib + 3] : alpha_g[(sbase + p) * 4 + 3];
    acc += bf2f(xb[c]) * a0 + bf2f(xb[128 + c]) * a1
         + bf2f(xb[256 + c]) * a2 + bf2f(xb[384 + c]) * a3;
  }
  float val = acc * 0.25f + bias[c];
  val = fmaxf(val, 0.f);
  float res = val + h_in[((size_t)t * NN + n) * 128 + c];
  red[c] = res; __syncthreads();
  for (int s2 = 64; s2 > 0; s2 >>= 1) { if (c < s2) red[c] += red[c + s2]; __syncthreads(); }
  float mu = red[0] * (1.f / 128.f); __syncthreads();
  float dv = res - mu;
  red[c] = dv * dv; __syncthreads();
  for (int s2 = 64; s2 > 0; s2 >>= 1) { if (c < s2) red[c] += red[c + s2]; __syncthreads(); }
  float rstd = rsqrtf(red[0] * (1.f / 128.f) + 1e-5f);
  h_out[((size_t)t * NN + n) * 128 + c] = dv * rstd * lng[c] + lnb[c];
}

// ---------------- graph pooling, two-stage ----------------
__global__ __launch_bounds__(128) void k_pool1(
    const float* __restrict__ h, const int* __restrict__ gs, float* __restrict__ part)
{
  int b = blockIdx.x, t = blockIdx.y, ch = blockIdx.z, c = threadIdx.x;
  int s0 = gs[b], s1 = gs[b + 1];
  int len = s1 - s0;
  int per = (len + PCH - 1) / PCH;
  int a0 = s0 + ch * per;
  int a1 = min(a0 + per, s1);
  float sum = 0.f, mx = -FLT_MAX;
  for (int n = a0; n < a1; ++n) {
    float v = h[((size_t)t * NN + n) * 128 + c];
    sum += v; mx = fmaxf(mx, v);
  }
  size_t o = (((size_t)(t * BB + b) * PCH + ch) * 2) * 128 + c;
  part[o] = sum; part[o + 128] = mx;
}

__global__ __launch_bounds__(128) void k_pool2(
    const float* __restrict__ part, const int* __restrict__ gs, float* __restrict__ pooled)
{
  int b = blockIdx.x, t = blockIdx.y, c = threadIdx.x;
  float sum = 0.f, mx = -FLT_MAX;
  for (int ch = 0; ch < PCH; ++ch) {
    size_t o = (((size_t)(t * BB + b) * PCH + ch) * 2) * 128 + c;
    sum += part[o]; mx = fmaxf(mx, part[o + 128]);
  }
  int cnt = gs[b + 1] - gs[b]; if (cnt < 1) cnt = 1;
  pooled[((size_t)t * BB + b) * 256 + c] = sum / (float)cnt;
  pooled[((size_t)t * BB + b) * 256 + 128 + c] = mx;
}

// ---------------- transpose tokens[T,B,:] -> app[B,T,:] ----------------
__global__ void k_app(const float* __restrict__ tokens, float* __restrict__ happ)
{
  int gid = blockIdx.x * 256 + threadIdx.x;
  if (gid >= BB * TT * TOKF) return;
  int b = gid / (TT * TOKF);
  int r = gid - b * (TT * TOKF);
  int t = r / TOKF, j = r - t * TOKF;
  happ[gid] = tokens[((size_t)t * BB + b) * TOKF + j];
}

// ---------------- motion diff output ----------------
__global__ void k_mot(const float* __restrict__ tokens, float* __restrict__ out2)
{
  int gid = blockIdx.x * 256 + threadIdx.x;
  if (gid >= BB * (TT - 1) * 256) return;
  int b = gid / ((TT - 1) * 256);
  int r = gid - b * ((TT - 1) * 256);
  int ti = r / 256, cc = r - ti * 256;
  out2[gid] = tokens[((size_t)(ti + 1) * BB + b) * TOKF + cc]
            - tokens[((size_t)ti * BB + b) * TOKF + cc];
}

// ---------------- tiny MHA ----------------
__global__ __launch_bounds__(64) void k_attn(const float* __restrict__ qkv, float* __restrict__ aout)
{
  __shared__ float qs[TT][64], ks[TT][64], vs[TT][64], sc[TT][TT];
  int h = blockIdx.x, b = blockIdx.y, d = threadIdx.x;
  for (int i = 0; i < TT; ++i) {
    size_t base = ((size_t)(b * TT + i)) * 1536 + h * 64 + d;
    qs[i][d] = qkv[base];
    ks[i][d] = qkv[base + 512];
    vs[i][d] = qkv[base + 1024];
  }
  __syncthreads();
  if (d < TT * TT) {
    int i = d / TT, j = d - i * TT;
    float s = 0.f;
    for (int k = 0; k < 64; ++k) s += qs[i][k] * ks[j][k];
    sc[i][j] = s * 0.125f;
  }
  __syncthreads();
  if (d < TT) {
    float mx = -FLT_MAX;
    for (int j = 0; j < TT; ++j) mx = fmaxf(mx, sc[d][j]);
    float sum = 0.f;
    for (int j = 0; j < TT; ++j) { float e = expf(sc[d][j] - mx); sc[d][j] = e; sum += e; }
    float inv = 1.f / sum;
    for (int j = 0; j < TT; ++j) sc[d][j] *= inv;
  }
  __syncthreads();
  for (int i = 0; i < TT; ++i) {
    float o = 0.f;
    for (int j = 0; j < TT; ++j) o += sc[i][j] * vs[j][d];
    aout[((size_t)(b * TT + i)) * 512 + h * 64 + d] = o;
  }
}

// ---------------- residual + LayerNorm (width 512) ----------------
__global__ __launch_bounds__(256) void k_res_ln(
    const float* __restrict__ a, const float* __restrict__ r,
    const float* __restrict__ g, const float* __restrict__ be,
    float* __restrict__ out)
{
  __shared__ float red[256];
  int rowi = blockIdx.x, tid = threadIdx.x;
  size_t base = (size_t)rowi * 512;
  float v0 = a[base + tid] + r[base + tid];
  float v1 = a[base + 256 + tid] + r[base + 256 + tid];
  red[tid] = v0 + v1; __syncthreads();
  for (int s2 = 128; s2 > 0; s2 >>= 1) { if (tid < s2) red[tid] += red[tid + s2]; __syncthreads(); }
  float mu = red[0] * (1.f / 512.f); __syncthreads();
  float d0 = v0 - mu, d1 = v1 - mu;
  red[tid] = d0 * d0 + d1 * d1; __syncthreads();
  for (int s2 = 128; s2 > 0; s2 >>= 1) { if (tid < s2) red[tid] += red[tid + s2]; __syncthreads(); }
  float rstd = rsqrtf(red[0] * (1.f / 512.f) + 1e-5f);
  out[base + tid]       = d0 * rstd * g[tid]       + be[tid];
  out[base + 256 + tid] = d1 * rstd * g[256 + tid] + be[256 + tid];
}

extern "C" void kernel_launch(void* const* d_in, const int* in_sizes, int n_in,
                              void* d_out, int out_size, void* d_ws, size_t ws_size,
                              hipStream_t stream)
{
  const float* x        = (const float*)d_in[0];
  const int*   eidx     = (const int*)  d_in[1];
  const float* eattr    = (const float*)d_in[2];
  const int*   batch    = (const int*)  d_in[3];
  const float* proj_w   = (const float*)d_in[4];
  const float* proj_b   = (const float*)d_in[5];
  const float* gat_wl   = (const float*)d_in[6];
  const float* gat_bl   = (const float*)d_in[7];
  const float* gat_wr   = (const float*)d_in[8];
  const float* gat_br   = (const float*)d_in[9];
  const float* gat_we   = (const float*)d_in[10];
  const float* gat_att  = (const float*)d_in[11];
  const float* gat_bias = (const float*)d_in[12];
  const float* ln_g     = (const float*)d_in[13];
  const float* ln_b     = (const float*)d_in[14];
  const float* n2t_w    = (const float*)d_in[15];
  const float* n2t_b    = (const float*)d_in[16];
  const float* tf_wqkv  = (const float*)d_in[17];
  const float* tf_bqkv  = (const float*)d_in[18];
  const float* tf_wo    = (const float*)d_in[19];
  const float* tf_bo    = (const float*)d_in[20];
  const float* tf_w1    = (const float*)d_in[21];
  const float* tf_b1    = (const float*)d_in[22];
  const float* tf_w2    = (const float*)d_in[23];
  const float* tf_b2    = (const float*)d_in[24];
  const float* tf_ln1g  = (const float*)d_in[25];
  const float* tf_ln1b  = (const float*)d_in[26];
  const float* tf_ln2g  = (const float*)d_in[27];
  const float* tf_ln2b  = (const float*)d_in[28];

  char* ws = (char*)d_ws;
  size_t off = 0;
  auto alloc = [&](size_t bytes) -> char* {
    char* p = ws + off;
    off += (bytes + 255) & ~(size_t)255;
    return p;
  };
  int*    cnt    = (int*)   alloc((size_t)TT * NN * 4);
  int*    row    = (int*)   alloc((size_t)TT * (NN + 1) * 4);
  int*    srcs   = (int*)   alloc((size_t)TT * EE * 4);
  int*    dsts   = (int*)   alloc((size_t)TT * EE * 4);
  int*    eids   = (int*)   alloc((size_t)TT * EE * 4);
  int*    gs     = (int*)   alloc((BB + 1) * 4);
  float*  h0     = (float*) alloc((size_t)TT * NN * 128 * 4);
  float*  h1     = (float*) alloc((size_t)TT * NN * 128 * 4);
  ushort* xlr    = (ushort*)alloc((size_t)TT * NN * 1024 * 2);   // bf16
  ushort* Wt     = (ushort*)alloc((size_t)1024 * 128 * 2);       // bf16 transposed weights
  float*  logits = (float*) alloc((size_t)TT * EE * 4 * 4);
  float*  alpha  = (float*) alloc((size_t)TT * EE * 4 * 4);
  float*  part   = (float*) alloc((size_t)TT * BB * PCH * 2 * 128 * 4);
  float*  pooled = (float*) alloc((size_t)TT * BB * 256 * 4);
  float*  tokens = (float*) alloc((size_t)TT * BB * 512 * 4);
  float*  happ   = (float*) alloc((size_t)BB * TT * 512 * 4);
  float*  happ2  = (float*) alloc((size_t)BB * TT * 512 * 4);
  float*  qkvb   = (float*) alloc((size_t)BB * TT * 1536 * 4);
  float*  aoutb  = (float*) alloc((size_t)BB * TT * 512 * 4);
  float*  aproj  = (float*) alloc((size_t)BB * TT * 512 * 4);
  float*  ffb    = (float*) alloc((size_t)BB * TT * 2048 * 4);
  float*  ff2o   = (float*) alloc((size_t)BB * TT * 512 * 4);
  if (off > ws_size) return;

  // split-K partial buffer aliases xlr (dead after GAT phase)
  float* P = (float*)xlr;

  // ---- CSR build per timestep ----
  hipMemsetAsync(cnt, 0, (size_t)TT * NN * 4, stream);
  k_hist<<<(TT * EE + 255) / 256, 256, 0, stream>>>(eidx, cnt);
  k_scan<<<TT, 256, 0, stream>>>(cnt, row);
  hipMemsetAsync(cnt, 0, (size_t)TT * NN * 4, stream);
  k_scatter<<<(TT * EE + 255) / 256, 256, 0, stream>>>(eidx, row, cnt, srcs, dsts, eids);
  k_gstart<<<(NN + 255) / 256, 256, 0, stream>>>(batch, gs);

  // ---- input projection ----
  gemm_tiled<<<dim3(2, (TT * NN) / 64), 256, 0, stream>>>(
      x, 128, proj_w, 128, proj_b, h0, 128, TT * NN, 128, 128);

  // ---- GAT layers ----
  float* hcur = h0; float* hnext = h1;
  for (int l = 0; l < 3; ++l) {
    const float* wl  = gat_wl  + (size_t)l * 128 * 512;
    const float* wr  = gat_wr  + (size_t)l * 128 * 512;
    const float* bl  = gat_bl  + (size_t)l * 512;
    const float* br  = gat_br  + (size_t)l * 512;
    const float* we  = gat_we  + (size_t)l * 2 * 512;
    const float* att = gat_att + (size_t)l * 512;
    k_wprep<<<(1024 * 128 + 255) / 256, 256, 0, stream>>>(wl, wr, Wt);
    gat_lr_gemm_mfma<<<dim3(16, 300), 256, 0, stream>>>(hcur, Wt, bl, br, xlr);
    k_edge_logits<<<dim3(EE / 4, TT), 256, 0, stream>>>(xlr, srcs, dsts, eids, eattr, we, att, logits);
    k_gat_aggregate<<<dim3(NN, TT), 128, 0, stream>>>(xlr, row, srcs, logits, alpha,
        gat_bias + l * 128, ln_g + l * 128, ln_b + l * 128, hcur, hnext);
    float* tmp = hcur; hcur = hnext; hnext = tmp;
  }

  // ---- pooling + token projection + motion diff ----
  k_pool1<<<dim3(BB, TT, PCH), 128, 0, stream>>>(hcur, gs, part);
  k_pool2<<<dim3(BB, TT), 128, 0, stream>>>(part, gs, pooled);
  gemm_part<<<dim3(512 / 32, 2), 256, 0, stream>>>(pooled, 256, n2t_w, 512, P, 512);
  k_part_reduce<<<(48 * 512 + 255) / 256, 256, 0, stream>>>(P, n2t_b, tokens, 48 * 512, 512, 2, 0);
  k_app<<<(BB * TT * TOKF + 255) / 256, 256, 0, stream>>>(tokens, happ);
  k_mot<<<(BB * (TT - 1) * 256 + 255) / 256, 256, 0, stream>>>(tokens, (float*)d_out + BB * TT * TOKF);

  // ---- transformer encoder ----
  float* hx = happ;
  for (int l = 0; l < 2; ++l) {
    gemm_part<<<dim3(1536 / 32, 4), 256, 0, stream>>>(hx, 512,
        tf_wqkv + (size_t)l * 512 * 1536, 1536, P, 1536);
    k_part_reduce<<<(48 * 1536 + 255) / 256, 256, 0, stream>>>(P, tf_bqkv + l * 1536, qkvb, 48 * 1536, 1536, 4, 0);
    k_attn<<<dim3(NHH, BB), 64, 0, stream>>>(qkvb, aoutb);
    gemm_part<<<dim3(512 / 32, 4), 256, 0, stream>>>(aoutb, 512,
        tf_wo + (size_t)l * 512 * 512, 512, P, 512);
    k_part_reduce<<<(48 * 512 + 255) / 256, 256, 0, stream>>>(P, tf_bo + l * 512, aproj, 48 * 512, 512, 4, 0);
    k_res_ln<<<BB * TT, 256, 0, stream>>>(aproj, hx, tf_ln1g + l * 512, tf_ln1b + l * 512, happ2);
    gemm_part<<<dim3(2048 / 32, 4), 256, 0, stream>>>(happ2, 512,
        tf_w1 + (size_t)l * 512 * 2048, 2048, P, 2048);
    k_part_reduce<<<(48 * 2048 + 255) / 256, 256, 0, stream>>>(P, tf_b1 + l * 2048, ffb, 48 * 2048, 2048, 4, 1);
    gemm_part<<<dim3(512 / 32, 16), 256, 0, stream>>>(ffb, 2048,
        tf_w2 + (size_t)l * 2048 * 512, 512, P, 512);
    k_part_reduce<<<(48 * 512 + 255) / 256, 256, 0, stream>>>(P, tf_b2 + l * 512, ff2o, 48 * 512, 512, 16, 0);
    float* dst = (l == 1) ? (float*)d_out : happ;
    k_res_ln<<<BB * TT, 256, 0, stream>>>(ff2o, happ2, tf_ln2g + l * 512, tf_ln2b + l * 512, dst);
    hx = happ;
  }
}